// Round 2
// baseline (5828.326 us; speedup 1.0000x reference)
//
#include <hip/hip_runtime.h>

#define HDIM 128
#define OFF_SPECIAL 2

// --- degree: deg[dst] += 1 per edge (int atomics; +1 self-loop added in k_dinv)
__global__ void k_deg(const int* __restrict__ dst, int E, int* __restrict__ deg) {
    int i = blockIdx.x * blockDim.x + threadIdx.x;
    if (i < E) atomicAdd(&deg[dst[i]], 1);
}

// --- dinv[i] = rsqrt(indeg + 1), in-place over the int deg buffer
__global__ void k_dinv(float* __restrict__ dinv, int N) {
    int i = blockIdx.x * blockDim.x + threadIdx.x;
    if (i < N) {
        float d = (float)(((const int*)dinv)[i]) + 1.0f;
        dinv[i] = rsqrtf(d);
    }
}

// --- scatter: agg[dst] += x[src] * dinv[src]*dinv[dst]. 32 lanes/edge, float4/lane.
__global__ void k_scatter(const int* __restrict__ src, const int* __restrict__ dst,
                          const float* __restrict__ dinv, int E,
                          const float* __restrict__ x, float* __restrict__ agg) {
    long long gid = (long long)blockIdx.x * blockDim.x + threadIdx.x;
    int e = (int)(gid >> 5);
    if (e >= E) return;
    int lane = (int)(gid & 31);
    int s = src[e], d = dst[e];
    float nrm = dinv[s] * dinv[d];
    const float4 xv = *(const float4*)(x + (size_t)s * HDIM + lane * 4);
    float* ap = agg + (size_t)d * HDIM + lane * 4;
    unsafeAtomicAdd(ap + 0, xv.x * nrm);
    unsafeAtomicAdd(ap + 1, xv.y * nrm);
    unsafeAtomicAdd(ap + 2, xv.z * nrm);
    unsafeAtomicAdd(ap + 3, xv.w * nrm);
}

// --- GEMM: out[n] = (agg[n] + xself[n]*dinv[n]^2) @ W + b, optional ReLU, fp32.
// 256 threads: col = tid&127, row-group = tid>>7 (4 rows each); 8 rows per chunk.
template <int RELU>
__global__ __launch_bounds__(256) void k_gemm(const float* __restrict__ agg,
                                              const float* __restrict__ xself,
                                              const float* __restrict__ dinv,
                                              const float* __restrict__ W,
                                              const float* __restrict__ bias,
                                              float* __restrict__ out, int N) {
    __shared__ __align__(16) float Wl[HDIM * HDIM];  // 64 KB
    __shared__ float inl[8][HDIM];                   // 4 KB
    int tid = threadIdx.x;

    for (int i = tid; i < HDIM * HDIM / 4; i += 256)
        ((float4*)Wl)[i] = ((const float4*)W)[i];

    int col = tid & 127;
    int rg  = tid >> 7;  // 0/1
    float bcol = bias[col];
    int nChunks = (N + 7) / 8;

    for (int c = blockIdx.x; c < nChunks; c += gridDim.x) {
        int r0 = c * 8;
        __syncthreads();  // covers W load on first iter, inl reuse afterwards
        for (int i = tid; i < 8 * HDIM; i += 256) {
            int r = i >> 7, k = i & 127;
            int row = r0 + r;
            float v = 0.0f;
            if (row < N) {
                float di = dinv[row];
                v = agg[(size_t)row * HDIM + k] +
                    xself[(size_t)row * HDIM + k] * di * di;
            }
            inl[r][k] = v;
        }
        __syncthreads();

        const float* i0 = inl[rg * 4 + 0];
        const float* i1 = inl[rg * 4 + 1];
        const float* i2 = inl[rg * 4 + 2];
        const float* i3 = inl[rg * 4 + 3];
        float a0 = 0.f, a1 = 0.f, a2 = 0.f, a3 = 0.f;
#pragma unroll 16
        for (int k = 0; k < HDIM; ++k) {
            float w = Wl[k * HDIM + col];
            a0 = fmaf(i0[k], w, a0);
            a1 = fmaf(i1[k], w, a1);
            a2 = fmaf(i2[k], w, a2);
            a3 = fmaf(i3[k], w, a3);
        }
        float acc[4] = {a0, a1, a2, a3};
#pragma unroll
        for (int r = 0; r < 4; ++r) {
            int row = r0 + rg * 4 + r;
            if (row < N) {
                float v = acc[r] + bcol;
                if (RELU) v = fmaxf(v, 0.0f);
                out[(size_t)row * HDIM + col] = v;
            }
        }
    }
}

// --- final gather: out[p] = seq[p]>=0 ? z[seq[p]] : emb[seq[p]+2+N]. 32 lanes/pos.
__global__ void k_gather(const int* __restrict__ seq, int P,
                         const float* __restrict__ z,
                         const float* __restrict__ emb, int N,
                         float* __restrict__ out) {
    int gid = blockIdx.x * blockDim.x + threadIdx.x;
    int p = gid >> 5, c = gid & 31;
    if (p >= P) return;
    int sv = seq[p];
    const float* row = (sv >= 0)
        ? (z + (size_t)sv * HDIM)
        : (emb + (size_t)(sv + OFF_SPECIAL + N) * HDIM);
    ((float4*)(out + (size_t)p * HDIM))[c] = ((const float4*)row)[c];
}

extern "C" void kernel_launch(void* const* d_in, const int* in_sizes, int n_in,
                              void* d_out, int out_size, void* d_ws, size_t ws_size,
                              hipStream_t stream) {
    const float* emb = (const float*)d_in[0];
    const float* W0  = (const float*)d_in[1];
    const float* b0  = (const float*)d_in[2];
    const float* W1  = (const float*)d_in[3];
    const float* b1  = (const float*)d_in[4];
    const int* ei  = (const int*)d_in[5];
    const int* seq = (const int*)d_in[6];

    int N = in_sizes[0] / HDIM - OFF_SPECIAL;   // 100000
    int E = in_sizes[5] / 2;                    // 1600000
    int P = in_sizes[6];                        // 32768
    const int* srcp = ei;
    const int* dstp = ei + E;

    // workspace layout: agg (51.2MB) | h (51.2MB) | dinv (0.4MB)  => ~103MB
    char* ws = (char*)d_ws;
    size_t aggB = (size_t)N * HDIM * sizeof(float);
    float* agg  = (float*)ws;
    float* hbuf = (float*)(ws + aggB);
    float* dinv = (float*)(ws + 2 * aggB);

    hipMemsetAsync(dinv, 0, (size_t)N * sizeof(int), stream);
    hipMemsetAsync(agg, 0, aggB, stream);

    int b256 = 256;
    k_deg<<<(E + 255) / 256, b256, 0, stream>>>(dstp, E, (int*)dinv);
    k_dinv<<<(N + 255) / 256, b256, 0, stream>>>(dinv, N);

    long long scatterThreads = (long long)E * 32;
    int scatterBlocks = (int)((scatterThreads + 255) / 256);

    // conv1: scatter from emb, then GEMM(+self term)+ReLU -> hbuf
    k_scatter<<<scatterBlocks, b256, 0, stream>>>(srcp, dstp, dinv, E, emb, agg);
    k_gemm<1><<<1024, b256, 0, stream>>>(agg, emb, dinv, W0, b0, hbuf, N);

    // conv2: re-zero agg, scatter from h, GEMM -> z (in-place over hbuf, row-safe)
    hipMemsetAsync(agg, 0, aggB, stream);
    k_scatter<<<scatterBlocks, b256, 0, stream>>>(srcp, dstp, dinv, E, hbuf, agg);
    k_gemm<0><<<1024, b256, 0, stream>>>(agg, hbuf, dinv, W1, b1, hbuf, N);

    // final gather
    k_gather<<<(P * 32 + 255) / 256, b256, 0, stream>>>(seq, P, hbuf, emb, N,
                                                        (float*)d_out);
}

// Round 3
// 1546.137 us; speedup vs baseline: 3.7696x; 3.7696x over previous
//
#include <hip/hip_runtime.h>

#define HDIM 128
#define OFF_SPECIAL 2

__device__ __forceinline__ float bf2f(unsigned short u) {
    union { unsigned int i; float f; } v;
    v.i = ((unsigned int)u) << 16;
    return v.f;
}
__device__ __forceinline__ unsigned short f2bf(float f) {
    union { float f; unsigned int i; } v;
    v.f = f;
    unsigned int x = v.i;
    x += 0x7FFFu + ((x >> 16) & 1u);   // RNE; data has no NaNs
    return (unsigned short)(x >> 16);
}

// --- in-degree count (self-loop added analytically in k_alloc)
__global__ void k_deg(const int* __restrict__ dst, int E, int* __restrict__ deg) {
    int i = blockIdx.x * blockDim.x + threadIdx.x;
    if (i < E) atomicAdd(&deg[dst[i]], 1);
}

// --- CSR range allocation: wave-level exclusive scan + 1 atomic/wave.
//     cur[i] = start offset for node i; dinv[i] = rsqrt(deg+1).
__global__ void k_alloc(const int* __restrict__ deg, int N,
                        int* __restrict__ cur, float* __restrict__ dinv,
                        int* __restrict__ counter) {
    int i = blockIdx.x * blockDim.x + threadIdx.x;
    int lane = threadIdx.x & 63;
    int d = (i < N) ? deg[i] : 0;
    int v = d;
#pragma unroll
    for (int off = 1; off < 64; off <<= 1) {
        int t = __shfl_up(v, off);
        if (lane >= off) v += t;
    }
    int total = __shfl(v, 63);
    int base = 0;
    if (lane == 63) base = atomicAdd(counter, total);
    base = __shfl(base, 63);
    if (i < N) {
        cur[i] = base + (v - d);                 // exclusive prefix within wave
        dinv[i] = rsqrtf((float)d + 1.0f);
    }
}

// --- bucket-fill adjacency: adj[slot] = src. After this, cur[i] = end offset.
__global__ void k_fill(const int* __restrict__ src, const int* __restrict__ dst, int E,
                       int* __restrict__ cur, int* __restrict__ adj) {
    int e = blockIdx.x * blockDim.x + threadIdx.x;
    if (e < E) {
        int slot = atomicAdd(&cur[dst[e]], 1);
        adj[slot] = src[e];
    }
}

// --- fused pull-conv + GEMM.
// Block = 256 thr (4 waves). Per chunk of 8 rows: wave w gathers rows 2w,2w+1
// (lane l covers cols 2l,2l+1) into LDS, then the block does 8x128 @ 128x128.
// INBF: x rows are bf16; OUTBF: output stored bf16. W/bias fp32, accum fp32.
template <int RELU, int INBF, int OUTBF>
__global__ __launch_bounds__(256) void k_conv_gemm(
        const void* __restrict__ xin, const int* __restrict__ deg,
        const int* __restrict__ end, const int* __restrict__ adj,
        const float* __restrict__ dinv,
        const float* __restrict__ W, const float* __restrict__ bias,
        void* __restrict__ out, int N) {
    __shared__ __align__(16) float Wl[HDIM * HDIM];  // 64 KB
    __shared__ float inl[8][HDIM];                   // 4 KB
    int tid = threadIdx.x;

    for (int i = tid; i < HDIM * HDIM / 4; i += 256)
        ((float4*)Wl)[i] = ((const float4*)W)[i];

    const float* xf = (const float*)xin;
    const unsigned short* xh = (const unsigned short*)xin;
    int lane = tid & 63;
    int wv = tid >> 6;       // wave 0..3
    int col = tid & 127;
    int rg = tid >> 7;       // 0/1
    float bcol = bias[col];
    int nChunks = (N + 7) / 8;

    for (int c = blockIdx.x; c < nChunks; c += gridDim.x) {
        int r0 = c * 8;
        __syncthreads();  // covers W load on first iter; inl reuse afterwards

        // ---- gather phase: wave wv owns rows rA,rB (wave-uniform degrees)
        {
            int rA = r0 + 2 * wv, rB = rA + 1;
            float aAx = 0.f, aAy = 0.f, aBx = 0.f, aBy = 0.f;
            int degA = 0, stA = 0, degB = 0, stB = 0;
            float dA = 0.f, dB = 0.f;
            size_t cix = 2 * (size_t)lane;
            if (rA < N) {
                degA = deg[rA]; stA = end[rA] - degA; dA = dinv[rA];
                size_t ix = (size_t)rA * HDIM + cix;
                float sc = dA * dA;  // self-loop term
                if (INBF) {
                    unsigned int u = *(const unsigned int*)(xh + ix);
                    aAx = bf2f((unsigned short)u) * sc;
                    aAy = bf2f((unsigned short)(u >> 16)) * sc;
                } else {
                    float2 xv = *(const float2*)(xf + ix);
                    aAx = xv.x * sc; aAy = xv.y * sc;
                }
            }
            if (rB < N) {
                degB = deg[rB]; stB = end[rB] - degB; dB = dinv[rB];
                size_t ix = (size_t)rB * HDIM + cix;
                float sc = dB * dB;
                if (INBF) {
                    unsigned int u = *(const unsigned int*)(xh + ix);
                    aBx = bf2f((unsigned short)u) * sc;
                    aBy = bf2f((unsigned short)(u >> 16)) * sc;
                } else {
                    float2 xv = *(const float2*)(xf + ix);
                    aBx = xv.x * sc; aBy = xv.y * sc;
                }
            }
            int m = degA > degB ? degA : degB;
            for (int t = 0; t < m; ++t) {
                if (t < degA) {  // wave-uniform branch
                    int s = adj[stA + t];
                    float nr = dinv[s] * dA;
                    size_t ix = (size_t)s * HDIM + cix;
                    if (INBF) {
                        unsigned int u = *(const unsigned int*)(xh + ix);
                        aAx = fmaf(bf2f((unsigned short)u), nr, aAx);
                        aAy = fmaf(bf2f((unsigned short)(u >> 16)), nr, aAy);
                    } else {
                        float2 xv = *(const float2*)(xf + ix);
                        aAx = fmaf(xv.x, nr, aAx);
                        aAy = fmaf(xv.y, nr, aAy);
                    }
                }
                if (t < degB) {
                    int s = adj[stB + t];
                    float nr = dinv[s] * dB;
                    size_t ix = (size_t)s * HDIM + cix;
                    if (INBF) {
                        unsigned int u = *(const unsigned int*)(xh + ix);
                        aBx = fmaf(bf2f((unsigned short)u), nr, aBx);
                        aBy = fmaf(bf2f((unsigned short)(u >> 16)), nr, aBy);
                    } else {
                        float2 xv = *(const float2*)(xf + ix);
                        aBx = fmaf(xv.x, nr, aBx);
                        aBy = fmaf(xv.y, nr, aBy);
                    }
                }
            }
            *(float2*)&inl[2 * wv + 0][2 * lane] = make_float2(aAx, aAy);
            *(float2*)&inl[2 * wv + 1][2 * lane] = make_float2(aBx, aBy);
        }
        __syncthreads();

        // ---- GEMM phase: 4 (row,col) outputs per thread
        const float* i0 = inl[rg * 4 + 0];
        const float* i1 = inl[rg * 4 + 1];
        const float* i2 = inl[rg * 4 + 2];
        const float* i3 = inl[rg * 4 + 3];
        float a0 = 0.f, a1 = 0.f, a2 = 0.f, a3 = 0.f;
#pragma unroll 16
        for (int k = 0; k < HDIM; ++k) {
            float w = Wl[k * HDIM + col];
            a0 = fmaf(i0[k], w, a0);
            a1 = fmaf(i1[k], w, a1);
            a2 = fmaf(i2[k], w, a2);
            a3 = fmaf(i3[k], w, a3);
        }
        float acc[4] = {a0, a1, a2, a3};
#pragma unroll
        for (int r = 0; r < 4; ++r) {
            int row = r0 + rg * 4 + r;
            if (row < N) {
                float v = acc[r] + bcol;
                if (RELU) v = fmaxf(v, 0.0f);
                if (OUTBF)
                    ((unsigned short*)out)[(size_t)row * HDIM + col] = f2bf(v);
                else
                    ((float*)out)[(size_t)row * HDIM + col] = v;
            }
        }
    }
}

// --- final gather: out[p] = seq[p]>=0 ? z[seq[p]] : emb[seq[p]+2+N]. 32 lanes/pos.
__global__ void k_gather(const int* __restrict__ seq, int P,
                         const float* __restrict__ z,
                         const float* __restrict__ emb, int N,
                         float* __restrict__ out) {
    int gid = blockIdx.x * blockDim.x + threadIdx.x;
    int p = gid >> 5, c = gid & 31;
    if (p >= P) return;
    int sv = seq[p];
    const float* row = (sv >= 0)
        ? (z + (size_t)sv * HDIM)
        : (emb + (size_t)(sv + OFF_SPECIAL + N) * HDIM);
    ((float4*)(out + (size_t)p * HDIM))[c] = ((const float4*)row)[c];
}

extern "C" void kernel_launch(void* const* d_in, const int* in_sizes, int n_in,
                              void* d_out, int out_size, void* d_ws, size_t ws_size,
                              hipStream_t stream) {
    const float* emb = (const float*)d_in[0];
    const float* W0  = (const float*)d_in[1];
    const float* b0  = (const float*)d_in[2];
    const float* W1  = (const float*)d_in[3];
    const float* b1  = (const float*)d_in[4];
    const int* ei  = (const int*)d_in[5];
    const int* seq = (const int*)d_in[6];

    int N = in_sizes[0] / HDIM - OFF_SPECIAL;   // 100000
    int E = in_sizes[5] / 2;                    // 1600000
    int P = in_sizes[6];                        // 32768
    const int* srcp = ei;
    const int* dstp = ei + E;

    // workspace: hbf(25.6M) z(51.2M) deg(0.4M) cur(0.4M) dinv(0.4M) adj(6.4M) ctr
    char* ws = (char*)d_ws;
    size_t off = 0;
    auto alloc = [&](size_t bytes) {
        void* p = ws + off;
        off = (off + bytes + 255) & ~(size_t)255;
        return p;
    };
    unsigned short* hbf = (unsigned short*)alloc((size_t)N * HDIM * sizeof(unsigned short));
    float* z    = (float*)alloc((size_t)N * HDIM * sizeof(float));
    int*   deg  = (int*)alloc((size_t)N * sizeof(int));
    int*   cur  = (int*)alloc((size_t)N * sizeof(int));
    float* dinv = (float*)alloc((size_t)N * sizeof(float));
    int*   adj  = (int*)alloc((size_t)E * sizeof(int));
    int*   ctr  = (int*)alloc(256);

    hipMemsetAsync(deg, 0, (size_t)N * sizeof(int), stream);
    hipMemsetAsync(ctr, 0, sizeof(int), stream);

    k_deg<<<(E + 255) / 256, 256, 0, stream>>>(dstp, E, deg);
    k_alloc<<<(N + 255) / 256, 256, 0, stream>>>(deg, N, cur, dinv, ctr);
    k_fill<<<(E + 255) / 256, 256, 0, stream>>>(srcp, dstp, E, cur, adj);

    // conv1 (+ReLU) -> h (bf16); conv2 -> z (fp32)
    k_conv_gemm<1, 0, 1><<<512, 256, 0, stream>>>(emb, deg, cur, adj, dinv,
                                                  W0, b0, hbf, N);
    k_conv_gemm<0, 1, 0><<<512, 256, 0, stream>>>(hbf, deg, cur, adj, dinv,
                                                  W1, b1, z, N);

    k_gather<<<(P * 32 + 255) / 256, 256, 0, stream>>>(seq, P, z, emb, N,
                                                       (float*)d_out);
}

// Round 4
// 698.912 us; speedup vs baseline: 8.3391x; 2.2122x over previous
//
#include <hip/hip_runtime.h>

#define HDIM 128
#define OFF_SPECIAL 2

__device__ __forceinline__ float bf2f(unsigned short u) {
    union { unsigned int i; float f; } v;
    v.i = ((unsigned int)u) << 16;
    return v.f;
}
__device__ __forceinline__ unsigned short f2bf(float f) {
    union { float f; unsigned int i; } v;
    v.f = f;
    unsigned int x = v.i;
    x += 0x7FFFu + ((x >> 16) & 1u);   // RNE; data has no NaNs
    return (unsigned short)(x >> 16);
}

// --- in-degree count (self-loop added analytically in k_alloc)
__global__ void k_deg(const int* __restrict__ dst, int E, int* __restrict__ deg) {
    int i = blockIdx.x * blockDim.x + threadIdx.x;
    if (i < E) atomicAdd(&deg[dst[i]], 1);
}

// --- CSR range allocation: wave-level exclusive scan + 1 atomic/wave.
__global__ void k_alloc(const int* __restrict__ deg, int N,
                        int* __restrict__ cur, float* __restrict__ dinv,
                        int* __restrict__ counter) {
    int i = blockIdx.x * blockDim.x + threadIdx.x;
    int lane = threadIdx.x & 63;
    int d = (i < N) ? deg[i] : 0;
    int v = d;
#pragma unroll
    for (int off = 1; off < 64; off <<= 1) {
        int t = __shfl_up(v, off);
        if (lane >= off) v += t;
    }
    int total = __shfl(v, 63);
    int base = 0;
    if (lane == 63) base = atomicAdd(counter, total);
    base = __shfl(base, 63);
    if (i < N) {
        cur[i] = base + (v - d);                 // exclusive prefix within wave
        dinv[i] = rsqrtf((float)d + 1.0f);
    }
}

// --- bucket-fill adjacency: adj[slot] = src. After this, cur[i] = end offset.
__global__ void k_fill(const int* __restrict__ src, const int* __restrict__ dst, int E,
                       int* __restrict__ cur, int* __restrict__ adj) {
    int e = blockIdx.x * blockDim.x + threadIdx.x;
    if (e < E) {
        int slot = atomicAdd(&cur[dst[e]], 1);
        adj[slot] = src[e];
    }
}

// --- fp32 -> bf16 row cast (first N*HDIM elems of emb)
__global__ void k_cast(const float* __restrict__ in, unsigned short* __restrict__ out,
                       int n4) {
    int i = blockIdx.x * blockDim.x + threadIdx.x;
    if (i >= n4) return;
    float4 v = ((const float4*)in)[i];
    ushort4 o;
    o.x = f2bf(v.x); o.y = f2bf(v.y); o.z = f2bf(v.z); o.w = f2bf(v.w);
    ((ushort4*)out)[i] = o;
}

// --- pull-conv aggregation: agg[row] = x[row]*dinv[row]^2 + sum_nbr x[s]*dinv[s]*dinv[row]
// One wave per row, lane l covers cols 2l,2l+1. 4-way unrolled neighbor loop for MLP.
template <int INBF>
__global__ __launch_bounds__(256, 8) void k_pull(
        const void* __restrict__ xin, const int* __restrict__ deg,
        const int* __restrict__ end, const int* __restrict__ adj,
        const float* __restrict__ dinv, float* __restrict__ agg, int N) {
    int row = blockIdx.x * 4 + (threadIdx.x >> 6);
    if (row >= N) return;
    int lane = threadIdx.x & 63;
    const unsigned short* xh = (const unsigned short*)xin;
    const float* xf = (const float*)xin;
    int d = deg[row];
    int st = end[row] - d;
    float dr = dinv[row];
    unsigned int cix = 2u * (unsigned int)lane;

    float ax, ay;
    {
        float sc = dr * dr;  // self-loop term
        if (INBF) {
            unsigned int u = *(const unsigned int*)(xh + (size_t)((unsigned)row * HDIM + cix));
            ax = bf2f((unsigned short)u) * sc;
            ay = bf2f((unsigned short)(u >> 16)) * sc;
        } else {
            float2 v = *(const float2*)(xf + (size_t)((unsigned)row * HDIM + cix));
            ax = v.x * sc; ay = v.y * sc;
        }
    }
    int t = 0;
    for (; t + 4 <= d; t += 4) {
        int s0 = adj[st + t + 0];
        int s1 = adj[st + t + 1];
        int s2 = adj[st + t + 2];
        int s3 = adj[st + t + 3];
        float n0 = dinv[s0] * dr, n1 = dinv[s1] * dr;
        float n2 = dinv[s2] * dr, n3 = dinv[s3] * dr;
        if (INBF) {
            unsigned int u0 = *(const unsigned int*)(xh + (size_t)((unsigned)s0 * HDIM + cix));
            unsigned int u1 = *(const unsigned int*)(xh + (size_t)((unsigned)s1 * HDIM + cix));
            unsigned int u2 = *(const unsigned int*)(xh + (size_t)((unsigned)s2 * HDIM + cix));
            unsigned int u3 = *(const unsigned int*)(xh + (size_t)((unsigned)s3 * HDIM + cix));
            ax = fmaf(bf2f((unsigned short)u0), n0, ax);
            ay = fmaf(bf2f((unsigned short)(u0 >> 16)), n0, ay);
            ax = fmaf(bf2f((unsigned short)u1), n1, ax);
            ay = fmaf(bf2f((unsigned short)(u1 >> 16)), n1, ay);
            ax = fmaf(bf2f((unsigned short)u2), n2, ax);
            ay = fmaf(bf2f((unsigned short)(u2 >> 16)), n2, ay);
            ax = fmaf(bf2f((unsigned short)u3), n3, ax);
            ay = fmaf(bf2f((unsigned short)(u3 >> 16)), n3, ay);
        } else {
            float2 v0 = *(const float2*)(xf + (size_t)((unsigned)s0 * HDIM + cix));
            float2 v1 = *(const float2*)(xf + (size_t)((unsigned)s1 * HDIM + cix));
            float2 v2 = *(const float2*)(xf + (size_t)((unsigned)s2 * HDIM + cix));
            float2 v3 = *(const float2*)(xf + (size_t)((unsigned)s3 * HDIM + cix));
            ax = fmaf(v0.x, n0, ax); ay = fmaf(v0.y, n0, ay);
            ax = fmaf(v1.x, n1, ax); ay = fmaf(v1.y, n1, ay);
            ax = fmaf(v2.x, n2, ax); ay = fmaf(v2.y, n2, ay);
            ax = fmaf(v3.x, n3, ax); ay = fmaf(v3.y, n3, ay);
        }
    }
    for (; t < d; ++t) {
        int s = adj[st + t];
        float nr = dinv[s] * dr;
        if (INBF) {
            unsigned int u = *(const unsigned int*)(xh + (size_t)((unsigned)s * HDIM + cix));
            ax = fmaf(bf2f((unsigned short)u), nr, ax);
            ay = fmaf(bf2f((unsigned short)(u >> 16)), nr, ay);
        } else {
            float2 v = *(const float2*)(xf + (size_t)((unsigned)s * HDIM + cix));
            ax = fmaf(v.x, nr, ax);
            ay = fmaf(v.y, nr, ay);
        }
    }
    *(float2*)(agg + (size_t)((unsigned)row * HDIM + cix)) = make_float2(ax, ay);
}

// --- GEMM: out[n] = agg[n] @ W + b (+ReLU). In-place (out==agg) is safe:
// each chunk is staged to LDS before its rows are overwritten; chunks disjoint.
template <int RELU, int OUTBF>
__global__ __launch_bounds__(256) void k_gemm(const float* __restrict__ agg,
                                              const float* __restrict__ W,
                                              const float* __restrict__ bias,
                                              void* __restrict__ out, int N) {
    __shared__ __align__(16) float Wl[HDIM * HDIM];  // 64 KB
    __shared__ __align__(16) float inl[8][HDIM];     // 4 KB
    int tid = threadIdx.x;

    for (int i = tid; i < HDIM * HDIM / 4; i += 256)
        ((float4*)Wl)[i] = ((const float4*)W)[i];

    int col = tid & 127;
    int rg  = tid >> 7;  // 0/1
    float bcol = bias[col];
    int nChunks = (N + 7) / 8;

    for (int c = blockIdx.x; c < nChunks; c += gridDim.x) {
        int r0 = c * 8;
        __syncthreads();  // covers W load on first iter; inl reuse afterwards
        {   // float4 staging: thread -> (row tid>>5, 4 cols at 4*(tid&31))
            int r = tid >> 5, k4 = (tid & 31) * 4;
            int row = r0 + r;
            float4 v = make_float4(0.f, 0.f, 0.f, 0.f);
            if (row < N) v = *(const float4*)(agg + (size_t)((unsigned)row * HDIM + k4));
            *(float4*)&inl[r][k4] = v;
        }
        __syncthreads();

        const float* i0 = inl[rg * 4 + 0];
        const float* i1 = inl[rg * 4 + 1];
        const float* i2 = inl[rg * 4 + 2];
        const float* i3 = inl[rg * 4 + 3];
        float a0 = 0.f, a1 = 0.f, a2 = 0.f, a3 = 0.f;
#pragma unroll 16
        for (int k = 0; k < HDIM; ++k) {
            float w = Wl[k * HDIM + col];
            a0 = fmaf(i0[k], w, a0);
            a1 = fmaf(i1[k], w, a1);
            a2 = fmaf(i2[k], w, a2);
            a3 = fmaf(i3[k], w, a3);
        }
        float acc[4] = {a0, a1, a2, a3};
#pragma unroll
        for (int r = 0; r < 4; ++r) {
            int row = r0 + rg * 4 + r;
            if (row < N) {
                float v = acc[r] + bcol;
                if (RELU) v = fmaxf(v, 0.0f);
                if (OUTBF)
                    ((unsigned short*)out)[(size_t)((unsigned)row * HDIM + col)] = f2bf(v);
                else
                    ((float*)out)[(size_t)((unsigned)row * HDIM + col)] = v;
            }
        }
    }
}

// --- final gather: out[p] = seq[p]>=0 ? z[seq[p]] : emb[seq[p]+2+N]. 32 lanes/pos.
__global__ void k_gather(const int* __restrict__ seq, int P,
                         const float* __restrict__ z,
                         const float* __restrict__ emb, int N,
                         float* __restrict__ out) {
    int gid = blockIdx.x * blockDim.x + threadIdx.x;
    int p = gid >> 5, c = gid & 31;
    if (p >= P) return;
    int sv = seq[p];
    const float* row = (sv >= 0)
        ? (z + (size_t)sv * HDIM)
        : (emb + (size_t)(sv + OFF_SPECIAL + N) * HDIM);
    ((float4*)(out + (size_t)p * HDIM))[c] = ((const float4*)row)[c];
}

extern "C" void kernel_launch(void* const* d_in, const int* in_sizes, int n_in,
                              void* d_out, int out_size, void* d_ws, size_t ws_size,
                              hipStream_t stream) {
    const float* emb = (const float*)d_in[0];
    const float* W0  = (const float*)d_in[1];
    const float* b0  = (const float*)d_in[2];
    const float* W1  = (const float*)d_in[3];
    const float* b1  = (const float*)d_in[4];
    const int* ei  = (const int*)d_in[5];
    const int* seq = (const int*)d_in[6];

    int N = in_sizes[0] / HDIM - OFF_SPECIAL;   // 100000
    int E = in_sizes[5] / 2;                    // 1600000
    int P = in_sizes[6];                        // 32768
    const int* srcp = ei;
    const int* dstp = ei + E;

    // workspace: agg/z(51.2M) hbf(25.6M) deg cur dinv(1.2M) adj(6.4M) ctr [embbf 25.6M]
    char* ws = (char*)d_ws;
    size_t off = 0;
    auto alloc = [&](size_t bytes) {
        void* p = ws + off;
        off = (off + bytes + 255) & ~(size_t)255;
        return p;
    };
    float* agg = (float*)alloc((size_t)N * HDIM * sizeof(float));  // also z (in-place)
    unsigned short* hbf = (unsigned short*)alloc((size_t)N * HDIM * sizeof(unsigned short));
    int*   deg  = (int*)alloc((size_t)N * sizeof(int));
    int*   cur  = (int*)alloc((size_t)N * sizeof(int));
    float* dinv = (float*)alloc((size_t)N * sizeof(float));
    int*   adj  = (int*)alloc((size_t)E * sizeof(int));
    int*   ctr  = (int*)alloc(256);
    size_t embbfB = (size_t)N * HDIM * sizeof(unsigned short);
    bool useEmbBf = (off + embbfB) <= ws_size;
    unsigned short* embbf = useEmbBf ? (unsigned short*)alloc(embbfB) : nullptr;

    hipMemsetAsync(deg, 0, (size_t)N * sizeof(int), stream);
    hipMemsetAsync(ctr, 0, sizeof(int), stream);

    k_deg<<<(E + 255) / 256, 256, 0, stream>>>(dstp, E, deg);
    k_alloc<<<(N + 255) / 256, 256, 0, stream>>>(deg, N, cur, dinv, ctr);
    k_fill<<<(E + 255) / 256, 256, 0, stream>>>(srcp, dstp, E, cur, adj);

    int pullBlocks = (N + 3) / 4;

    // conv1: pull (+self) -> agg; GEMM+ReLU -> hbf (bf16)
    if (useEmbBf) {
        int n4 = N * HDIM / 4;
        k_cast<<<(n4 + 255) / 256, 256, 0, stream>>>(emb, embbf, n4);
        k_pull<1><<<pullBlocks, 256, 0, stream>>>(embbf, deg, cur, adj, dinv, agg, N);
    } else {
        k_pull<0><<<pullBlocks, 256, 0, stream>>>(emb, deg, cur, adj, dinv, agg, N);
    }
    k_gemm<1, 1><<<1024, 256, 0, stream>>>(agg, W0, b0, hbf, N);

    // conv2: pull from hbf -> agg (full overwrite); GEMM in-place -> z (= agg)
    k_pull<1><<<pullBlocks, 256, 0, stream>>>(hbf, deg, cur, adj, dinv, agg, N);
    k_gemm<0, 0><<<1024, 256, 0, stream>>>(agg, W1, b1, agg, N);

    // final gather
    k_gather<<<(P * 32 + 255) / 256, 256, 0, stream>>>(seq, P, agg, emb, N,
                                                       (float*)d_out);
}

// Round 5
// 494.443 us; speedup vs baseline: 11.7877x; 1.4135x over previous
//
#include <hip/hip_runtime.h>

#define HDIM 128
#define OFF_SPECIAL 2

typedef __attribute__((ext_vector_type(8))) short bf16x8;
typedef __attribute__((ext_vector_type(4))) float f32x4;

__device__ __forceinline__ float bf2f(unsigned short u) {
    union { unsigned int i; float f; } v;
    v.i = ((unsigned int)u) << 16;
    return v.f;
}
__device__ __forceinline__ unsigned short f2bf(float f) {
    union { float f; unsigned int i; } v;
    v.f = f;
    unsigned int x = v.i;
    x += 0x7FFFu + ((x >> 16) & 1u);   // RNE; data has no NaNs
    return (unsigned short)(x >> 16);
}

// --- in-degree count (self-loop added analytically in k_alloc)
__global__ void k_deg(const int* __restrict__ dst, int E, int* __restrict__ deg) {
    int i = blockIdx.x * blockDim.x + threadIdx.x;
    if (i < E) atomicAdd(&deg[dst[i]], 1);
}

// --- CSR range allocation: wave-level exclusive scan + 1 atomic/wave.
__global__ void k_alloc(const int* __restrict__ deg, int N,
                        int* __restrict__ cur, float* __restrict__ dinv,
                        int* __restrict__ counter) {
    int i = blockIdx.x * blockDim.x + threadIdx.x;
    int lane = threadIdx.x & 63;
    int d = (i < N) ? deg[i] : 0;
    int v = d;
#pragma unroll
    for (int off = 1; off < 64; off <<= 1) {
        int t = __shfl_up(v, off);
        if (lane >= off) v += t;
    }
    int total = __shfl(v, 63);
    int base = 0;
    if (lane == 63) base = atomicAdd(counter, total);
    base = __shfl(base, 63);
    if (i < N) {
        cur[i] = base + (v - d);                 // exclusive prefix within wave
        dinv[i] = rsqrtf((float)d + 1.0f);
    }
}

// --- bucket-fill adjacency: adj[slot] = src. After this, cur[i] = end offset.
__global__ void k_fill(const int* __restrict__ src, const int* __restrict__ dst, int E,
                       int* __restrict__ cur, int* __restrict__ adj) {
    int e = blockIdx.x * blockDim.x + threadIdx.x;
    if (e < E) {
        int slot = atomicAdd(&cur[dst[e]], 1);
        adj[slot] = src[e];
    }
}

// --- fp32 -> bf16 cast (first N*HDIM elems of emb)
__global__ void k_cast(const float* __restrict__ in, unsigned short* __restrict__ out,
                       int n4) {
    int i = blockIdx.x * blockDim.x + threadIdx.x;
    if (i >= n4) return;
    float4 v = ((const float4*)in)[i];
    ushort4 o;
    o.x = f2bf(v.x); o.y = f2bf(v.y); o.z = f2bf(v.z); o.w = f2bf(v.w);
    ((ushort4*)out)[i] = o;
}

// --- pull-conv: agg[row] = x[row]*dinv[row]^2 + sum_nbr x[s]*dinv[s]*dinv[row]
// x bf16, agg bf16. One wave per row, lane l covers cols 2l,2l+1. 4-way MLP unroll.
__global__ __launch_bounds__(256, 8) void k_pull(
        const unsigned short* __restrict__ x, const int* __restrict__ deg,
        const int* __restrict__ end, const int* __restrict__ adj,
        const float* __restrict__ dinv, unsigned short* __restrict__ agg, int N) {
    int row = blockIdx.x * 4 + (threadIdx.x >> 6);
    if (row >= N) return;
    int lane = threadIdx.x & 63;
    int d = deg[row];
    int st = end[row] - d;
    float dr = dinv[row];
    unsigned int cix = 2u * (unsigned int)lane;

    float ax, ay;
    {
        float sc = dr * dr;  // self-loop term
        unsigned int u = *(const unsigned int*)(x + (size_t)((unsigned)row * HDIM + cix));
        ax = bf2f((unsigned short)u) * sc;
        ay = bf2f((unsigned short)(u >> 16)) * sc;
    }
    int t = 0;
    for (; t + 4 <= d; t += 4) {
        int s0 = adj[st + t + 0];
        int s1 = adj[st + t + 1];
        int s2 = adj[st + t + 2];
        int s3 = adj[st + t + 3];
        float n0 = dinv[s0] * dr, n1 = dinv[s1] * dr;
        float n2 = dinv[s2] * dr, n3 = dinv[s3] * dr;
        unsigned int u0 = *(const unsigned int*)(x + (size_t)((unsigned)s0 * HDIM + cix));
        unsigned int u1 = *(const unsigned int*)(x + (size_t)((unsigned)s1 * HDIM + cix));
        unsigned int u2 = *(const unsigned int*)(x + (size_t)((unsigned)s2 * HDIM + cix));
        unsigned int u3 = *(const unsigned int*)(x + (size_t)((unsigned)s3 * HDIM + cix));
        ax = fmaf(bf2f((unsigned short)u0), n0, ax);
        ay = fmaf(bf2f((unsigned short)(u0 >> 16)), n0, ay);
        ax = fmaf(bf2f((unsigned short)u1), n1, ax);
        ay = fmaf(bf2f((unsigned short)(u1 >> 16)), n1, ay);
        ax = fmaf(bf2f((unsigned short)u2), n2, ax);
        ay = fmaf(bf2f((unsigned short)(u2 >> 16)), n2, ay);
        ax = fmaf(bf2f((unsigned short)u3), n3, ax);
        ay = fmaf(bf2f((unsigned short)(u3 >> 16)), n3, ay);
    }
    for (; t < d; ++t) {
        int s = adj[st + t];
        float nr = dinv[s] * dr;
        unsigned int u = *(const unsigned int*)(x + (size_t)((unsigned)s * HDIM + cix));
        ax = fmaf(bf2f((unsigned short)u), nr, ax);
        ay = fmaf(bf2f((unsigned short)(u >> 16)), nr, ay);
    }
    unsigned int pack = (unsigned int)f2bf(ax) | ((unsigned int)f2bf(ay) << 16);
    *(unsigned int*)(agg + (size_t)((unsigned)row * HDIM + cix)) = pack;
}

// --- MFMA GEMM: out[N][128] = A[N][128](bf16) @ W[128][128](fp32->bf16) + b (+ReLU).
// Wave computes a 16-row stripe; 8 col-tiles x 4 K-steps of 16x16x32 MFMA.
// In-place (out==A) safe: wave loads its A rows to regs before any store; chunks disjoint.
// Tail chunks overread <8KB past A (stays inside workspace); stores row-guarded.
template <int RELU>
__global__ __launch_bounds__(256) void k_gemm_mfma(
        const unsigned short* __restrict__ A, const float* __restrict__ W,
        const float* __restrict__ bias, unsigned short* __restrict__ out, int N) {
    __shared__ __align__(16) unsigned short Wt[HDIM * 136];  // [n][k], pad->34.8 KB
    int tid = threadIdx.x;
    for (int i = tid; i < HDIM * HDIM; i += 256) {
        int k = i >> 7, n = i & 127;
        Wt[n * 136 + k] = f2bf(W[i]);   // W[k][n] row-major
    }
    int lane = tid & 63;
    int wv = tid >> 6;
    int n15 = lane & 15, q = lane >> 4;
    float bv[8];
#pragma unroll
    for (int ct = 0; ct < 8; ++ct) bv[ct] = bias[ct * 16 + n15];
    __syncthreads();

    int nChunks = (N + 63) / 64;
    for (int c = blockIdx.x; c < nChunks; c += gridDim.x) {
        int row0 = c * 64 + wv * 16;
        const unsigned short* arow = A + (size_t)(row0 + n15) * HDIM + q * 8;
        bf16x8 a0 = *(const bf16x8*)(arow);
        bf16x8 a1 = *(const bf16x8*)(arow + 32);
        bf16x8 a2 = *(const bf16x8*)(arow + 64);
        bf16x8 a3 = *(const bf16x8*)(arow + 96);
#pragma unroll
        for (int ct = 0; ct < 8; ++ct) {
            const unsigned short* wrow = &Wt[(ct * 16 + n15) * 136 + q * 8];
            f32x4 acc = {0.f, 0.f, 0.f, 0.f};
            acc = __builtin_amdgcn_mfma_f32_16x16x32_bf16(a0, *(const bf16x8*)(wrow),      acc, 0, 0, 0);
            acc = __builtin_amdgcn_mfma_f32_16x16x32_bf16(a1, *(const bf16x8*)(wrow + 32), acc, 0, 0, 0);
            acc = __builtin_amdgcn_mfma_f32_16x16x32_bf16(a2, *(const bf16x8*)(wrow + 64), acc, 0, 0, 0);
            acc = __builtin_amdgcn_mfma_f32_16x16x32_bf16(a3, *(const bf16x8*)(wrow + 96), acc, 0, 0, 0);
#pragma unroll
            for (int r = 0; r < 4; ++r) {
                int row = row0 + q * 4 + r;
                if (row < N) {
                    float v = acc[r] + bv[ct];
                    if (RELU) v = fmaxf(v, 0.0f);
                    out[(size_t)row * HDIM + ct * 16 + n15] = f2bf(v);
                }
            }
        }
    }
}

// --- final gather: out[p] = seq[p]>=0 ? z[seq[p]] (bf16) : emb[seq[p]+2+N] (fp32).
__global__ void k_gather(const int* __restrict__ seq, int P,
                         const unsigned short* __restrict__ z,
                         const float* __restrict__ emb, int N,
                         float* __restrict__ out) {
    int gid = blockIdx.x * blockDim.x + threadIdx.x;
    int p = gid >> 5, c = gid & 31;
    if (p >= P) return;
    int sv = seq[p];
    float4 v;
    if (sv >= 0) {
        uint2 u = *(const uint2*)(z + (size_t)sv * HDIM + c * 4);
        v = make_float4(bf2f((unsigned short)u.x), bf2f((unsigned short)(u.x >> 16)),
                        bf2f((unsigned short)u.y), bf2f((unsigned short)(u.y >> 16)));
    } else {
        v = *(const float4*)(emb + (size_t)(sv + OFF_SPECIAL + N) * HDIM + c * 4);
    }
    *(float4*)(out + (size_t)p * HDIM + c * 4) = v;
}

extern "C" void kernel_launch(void* const* d_in, const int* in_sizes, int n_in,
                              void* d_out, int out_size, void* d_ws, size_t ws_size,
                              hipStream_t stream) {
    const float* emb = (const float*)d_in[0];
    const float* W0  = (const float*)d_in[1];
    const float* b0  = (const float*)d_in[2];
    const float* W1  = (const float*)d_in[3];
    const float* b1  = (const float*)d_in[4];
    const int* ei  = (const int*)d_in[5];
    const int* seq = (const int*)d_in[6];

    int N = in_sizes[0] / HDIM - OFF_SPECIAL;   // 100000
    int E = in_sizes[5] / 2;                    // 1600000
    int P = in_sizes[6];                        // 32768
    const int* srcp = ei;
    const int* dstp = ei + E;

    // workspace: embbf 25.6 | aggbf 25.6 | hbf 25.6 | adj 6.4 | deg/cur/dinv 1.2 | ctr
    //            => ~84.5 MB total (<= 84.9 MB proven safe)
    char* ws = (char*)d_ws;
    size_t off = 0;
    auto alloc = [&](size_t bytes) {
        void* p = ws + off;
        off = (off + bytes + 255) & ~(size_t)255;
        return p;
    };
    unsigned short* embbf = (unsigned short*)alloc((size_t)N * HDIM * sizeof(unsigned short));
    unsigned short* aggbf = (unsigned short*)alloc((size_t)N * HDIM * sizeof(unsigned short));
    unsigned short* hbf   = (unsigned short*)alloc((size_t)N * HDIM * sizeof(unsigned short));
    int*   adj  = (int*)alloc((size_t)E * sizeof(int));
    int*   deg  = (int*)alloc((size_t)N * sizeof(int));
    int*   cur  = (int*)alloc((size_t)N * sizeof(int));
    float* dinv = (float*)alloc((size_t)N * sizeof(float));
    int*   ctr  = (int*)alloc(256);

    hipMemsetAsync(deg, 0, (size_t)N * sizeof(int), stream);
    hipMemsetAsync(ctr, 0, sizeof(int), stream);

    k_deg<<<(E + 255) / 256, 256, 0, stream>>>(dstp, E, deg);
    k_alloc<<<(N + 255) / 256, 256, 0, stream>>>(deg, N, cur, dinv, ctr);
    k_fill<<<(E + 255) / 256, 256, 0, stream>>>(srcp, dstp, E, cur, adj);

    int n4 = N * HDIM / 4;
    k_cast<<<(n4 + 255) / 256, 256, 0, stream>>>(emb, embbf, n4);

    int pullBlocks = (N + 3) / 4;

    // conv1: pull(embbf) -> aggbf; MFMA GEMM+ReLU -> hbf
    k_pull<<<pullBlocks, 256, 0, stream>>>(embbf, deg, cur, adj, dinv, aggbf, N);
    k_gemm_mfma<1><<<640, 256, 0, stream>>>(aggbf, W0, b0, hbf, N);

    // conv2: pull(hbf) -> aggbf; MFMA GEMM in-place -> z (= aggbf)
    k_pull<<<pullBlocks, 256, 0, stream>>>(hbf, deg, cur, adj, dinv, aggbf, N);
    k_gemm_mfma<0><<<640, 256, 0, stream>>>(aggbf, W1, b1, aggbf, N);

    // final gather
    k_gather<<<(P * 32 + 255) / 256, 256, 0, stream>>>(seq, P, aggbf, emb, N,
                                                       (float*)d_out);
}

// Round 6
// 460.599 us; speedup vs baseline: 12.6538x; 1.0735x over previous
//
#include <hip/hip_runtime.h>

#define HDIM 128
#define OFF_SPECIAL 2
#define BSTRIDE 48   // bucket slots per node; deg~Poisson(16), P(deg>=48)~5e-11

typedef __attribute__((ext_vector_type(8))) short bf16x8;
typedef __attribute__((ext_vector_type(4))) float f32x4;

__device__ __forceinline__ float bf2f(unsigned short u) {
    union { unsigned int i; float f; } v;
    v.i = ((unsigned int)u) << 16;
    return v.f;
}
__device__ __forceinline__ unsigned short f2bf(float f) {
    union { float f; unsigned int i; } v;
    v.f = f;
    unsigned int x = v.i;
    x += 0x7FFFu + ((x >> 16) & 1u);   // RNE; data has no NaNs
    return (unsigned short)(x >> 16);
}

// --- one-pass bucket CSR: adjB[dst*BSTRIDE + slot] = src; cnt[dst] counts degree.
__global__ void k_fill_bucket(const int* __restrict__ src, const int* __restrict__ dst,
                              int E, int* __restrict__ cnt, int* __restrict__ adjB) {
    int e = blockIdx.x * blockDim.x + threadIdx.x;
    if (e < E) {
        int d = dst[e];
        int slot = atomicAdd(&cnt[d], 1);
        if (slot < BSTRIDE) adjB[d * BSTRIDE + slot] = src[e];
    }
}

// --- dinv[i] = rsqrt(deg+1) from bucket counts
__global__ void k_dinv(const int* __restrict__ cnt, float* __restrict__ dinv, int N) {
    int i = blockIdx.x * blockDim.x + threadIdx.x;
    if (i < N) dinv[i] = rsqrtf((float)cnt[i] + 1.0f);
}

// --- pull-conv: agg[row] = x[row]*dinv[row]^2 + sum_nbr x[s]*dinv[s]*dinv[row]
// INBF: x bf16 else fp32. agg bf16. One wave per row, lane l covers cols 2l,2l+1.
template <int INBF>
__global__ __launch_bounds__(256, 8) void k_pull(
        const void* __restrict__ xin, const int* __restrict__ cnt,
        const int* __restrict__ adjB, const float* __restrict__ dinv,
        unsigned short* __restrict__ agg, int N) {
    int row = blockIdx.x * 4 + (threadIdx.x >> 6);
    if (row >= N) return;
    int lane = threadIdx.x & 63;
    const unsigned short* xh = (const unsigned short*)xin;
    const float* xf = (const float*)xin;
    int d = cnt[row];
    if (d > BSTRIDE) d = BSTRIDE;
    const int* nbr = adjB + row * BSTRIDE;
    float dr = dinv[row];
    unsigned int cix = 2u * (unsigned int)lane;

    float ax, ay;
    {
        float sc = dr * dr;  // self-loop term
        if (INBF) {
            unsigned int u = *(const unsigned int*)(xh + (size_t)((unsigned)row * HDIM + cix));
            ax = bf2f((unsigned short)u) * sc;
            ay = bf2f((unsigned short)(u >> 16)) * sc;
        } else {
            float2 v = *(const float2*)(xf + (size_t)((unsigned)row * HDIM + cix));
            ax = v.x * sc; ay = v.y * sc;
        }
    }
    int t = 0;
    for (; t + 4 <= d; t += 4) {
        int s0 = nbr[t + 0];
        int s1 = nbr[t + 1];
        int s2 = nbr[t + 2];
        int s3 = nbr[t + 3];
        float n0 = dinv[s0] * dr, n1 = dinv[s1] * dr;
        float n2 = dinv[s2] * dr, n3 = dinv[s3] * dr;
        if (INBF) {
            unsigned int u0 = *(const unsigned int*)(xh + (size_t)((unsigned)s0 * HDIM + cix));
            unsigned int u1 = *(const unsigned int*)(xh + (size_t)((unsigned)s1 * HDIM + cix));
            unsigned int u2 = *(const unsigned int*)(xh + (size_t)((unsigned)s2 * HDIM + cix));
            unsigned int u3 = *(const unsigned int*)(xh + (size_t)((unsigned)s3 * HDIM + cix));
            ax = fmaf(bf2f((unsigned short)u0), n0, ax);
            ay = fmaf(bf2f((unsigned short)(u0 >> 16)), n0, ay);
            ax = fmaf(bf2f((unsigned short)u1), n1, ax);
            ay = fmaf(bf2f((unsigned short)(u1 >> 16)), n1, ay);
            ax = fmaf(bf2f((unsigned short)u2), n2, ax);
            ay = fmaf(bf2f((unsigned short)(u2 >> 16)), n2, ay);
            ax = fmaf(bf2f((unsigned short)u3), n3, ax);
            ay = fmaf(bf2f((unsigned short)(u3 >> 16)), n3, ay);
        } else {
            float2 v0 = *(const float2*)(xf + (size_t)((unsigned)s0 * HDIM + cix));
            float2 v1 = *(const float2*)(xf + (size_t)((unsigned)s1 * HDIM + cix));
            float2 v2 = *(const float2*)(xf + (size_t)((unsigned)s2 * HDIM + cix));
            float2 v3 = *(const float2*)(xf + (size_t)((unsigned)s3 * HDIM + cix));
            ax = fmaf(v0.x, n0, ax); ay = fmaf(v0.y, n0, ay);
            ax = fmaf(v1.x, n1, ax); ay = fmaf(v1.y, n1, ay);
            ax = fmaf(v2.x, n2, ax); ay = fmaf(v2.y, n2, ay);
            ax = fmaf(v3.x, n3, ax); ay = fmaf(v3.y, n3, ay);
        }
    }
    for (; t < d; ++t) {
        int s = nbr[t];
        float nr = dinv[s] * dr;
        if (INBF) {
            unsigned int u = *(const unsigned int*)(xh + (size_t)((unsigned)s * HDIM + cix));
            ax = fmaf(bf2f((unsigned short)u), nr, ax);
            ay = fmaf(bf2f((unsigned short)(u >> 16)), nr, ay);
        } else {
            float2 v = *(const float2*)(xf + (size_t)((unsigned)s * HDIM + cix));
            ax = fmaf(v.x, nr, ax);
            ay = fmaf(v.y, nr, ay);
        }
    }
    unsigned int pack = (unsigned int)f2bf(ax) | ((unsigned int)f2bf(ay) << 16);
    *(unsigned int*)(agg + (size_t)((unsigned)row * HDIM + cix)) = pack;
}

// --- MFMA GEMM: out[N][128] = A[N][128](bf16) @ W[128][128](fp32->bf16) + b (+ReLU).
// Wave computes a 16-row stripe; 8 col-tiles x 4 K-steps of 16x16x32 MFMA.
// In-place (out==A) safe: each output row depends only on its own input row,
// which the owning wave loads to registers before any store. Tail overreads
// stay inside the workspace; stores are row-guarded.
template <int RELU>
__global__ __launch_bounds__(256) void k_gemm_mfma(
        const unsigned short* __restrict__ A, const float* __restrict__ W,
        const float* __restrict__ bias, unsigned short* __restrict__ out, int N) {
    __shared__ __align__(16) unsigned short Wt[HDIM * 136];  // [n][k], pad->34.8 KB
    int tid = threadIdx.x;
    for (int i = tid; i < HDIM * HDIM; i += 256) {
        int k = i >> 7, n = i & 127;
        Wt[n * 136 + k] = f2bf(W[i]);   // W[k][n] row-major
    }
    int lane = tid & 63;
    int wv = tid >> 6;
    int n15 = lane & 15, q = lane >> 4;
    float bv[8];
#pragma unroll
    for (int ct = 0; ct < 8; ++ct) bv[ct] = bias[ct * 16 + n15];
    __syncthreads();

    int nChunks = (N + 63) / 64;
    for (int c = blockIdx.x; c < nChunks; c += gridDim.x) {
        int row0 = c * 64 + wv * 16;
        const unsigned short* arow = A + (size_t)(row0 + n15) * HDIM + q * 8;
        bf16x8 a0 = *(const bf16x8*)(arow);
        bf16x8 a1 = *(const bf16x8*)(arow + 32);
        bf16x8 a2 = *(const bf16x8*)(arow + 64);
        bf16x8 a3 = *(const bf16x8*)(arow + 96);
#pragma unroll
        for (int ct = 0; ct < 8; ++ct) {
            const unsigned short* wrow = &Wt[(ct * 16 + n15) * 136 + q * 8];
            f32x4 acc = {0.f, 0.f, 0.f, 0.f};
            acc = __builtin_amdgcn_mfma_f32_16x16x32_bf16(a0, *(const bf16x8*)(wrow),      acc, 0, 0, 0);
            acc = __builtin_amdgcn_mfma_f32_16x16x32_bf16(a1, *(const bf16x8*)(wrow + 32), acc, 0, 0, 0);
            acc = __builtin_amdgcn_mfma_f32_16x16x32_bf16(a2, *(const bf16x8*)(wrow + 64), acc, 0, 0, 0);
            acc = __builtin_amdgcn_mfma_f32_16x16x32_bf16(a3, *(const bf16x8*)(wrow + 96), acc, 0, 0, 0);
#pragma unroll
            for (int r = 0; r < 4; ++r) {
                int row = row0 + q * 4 + r;
                if (row < N) {
                    float v = acc[r] + bv[ct];
                    if (RELU) v = fmaxf(v, 0.0f);
                    out[(size_t)row * HDIM + ct * 16 + n15] = f2bf(v);
                }
            }
        }
    }
}

// --- final gather: out[p] = seq[p]>=0 ? z[seq[p]] (bf16) : emb[seq[p]+2+N] (fp32).
__global__ void k_gather(const int* __restrict__ seq, int P,
                         const unsigned short* __restrict__ z,
                         const float* __restrict__ emb, int N,
                         float* __restrict__ out) {
    int gid = blockIdx.x * blockDim.x + threadIdx.x;
    int p = gid >> 5, c = gid & 31;
    if (p >= P) return;
    int sv = seq[p];
    float4 v;
    if (sv >= 0) {
        uint2 u = *(const uint2*)(z + (size_t)sv * HDIM + c * 4);
        v = make_float4(bf2f((unsigned short)u.x), bf2f((unsigned short)(u.x >> 16)),
                        bf2f((unsigned short)u.y), bf2f((unsigned short)(u.y >> 16)));
    } else {
        v = *(const float4*)(emb + (size_t)(sv + OFF_SPECIAL + N) * HDIM + c * 4);
    }
    *(float4*)(out + (size_t)p * HDIM + c * 4) = v;
}

extern "C" void kernel_launch(void* const* d_in, const int* in_sizes, int n_in,
                              void* d_out, int out_size, void* d_ws, size_t ws_size,
                              hipStream_t stream) {
    const float* emb = (const float*)d_in[0];
    const float* W0  = (const float*)d_in[1];
    const float* b0  = (const float*)d_in[2];
    const float* W1  = (const float*)d_in[3];
    const float* b1  = (const float*)d_in[4];
    const int* ei  = (const int*)d_in[5];
    const int* seq = (const int*)d_in[6];

    int N = in_sizes[0] / HDIM - OFF_SPECIAL;   // 100000
    int E = in_sizes[5] / 2;                    // 1600000
    int P = in_sizes[6];                        // 32768
    const int* srcp = ei;
    const int* dstp = ei + E;

    // workspace: aggbf 25.6 | hbf 25.6 | adjB 19.2 | cnt 0.4 | dinv 0.4  => ~71.3 MB
    char* ws = (char*)d_ws;
    size_t off = 0;
    auto alloc = [&](size_t bytes) {
        void* p = ws + off;
        off = (off + bytes + 255) & ~(size_t)255;
        return p;
    };
    unsigned short* aggbf = (unsigned short*)alloc((size_t)N * HDIM * sizeof(unsigned short));
    unsigned short* hbf   = (unsigned short*)alloc((size_t)N * HDIM * sizeof(unsigned short));
    int*   adjB = (int*)alloc((size_t)N * BSTRIDE * sizeof(int));
    int*   cnt  = (int*)alloc((size_t)N * sizeof(int));
    float* dinv = (float*)alloc((size_t)N * sizeof(float));

    hipMemsetAsync(cnt, 0, (size_t)N * sizeof(int), stream);

    k_fill_bucket<<<(E + 255) / 256, 256, 0, stream>>>(srcp, dstp, E, cnt, adjB);
    k_dinv<<<(N + 255) / 256, 256, 0, stream>>>(cnt, dinv, N);

    int pullBlocks = (N + 3) / 4;

    // conv1: pull(emb fp32) -> aggbf; MFMA GEMM+ReLU -> hbf
    k_pull<0><<<pullBlocks, 256, 0, stream>>>(emb, cnt, adjB, dinv, aggbf, N);
    k_gemm_mfma<1><<<640, 256, 0, stream>>>(aggbf, W0, b0, hbf, N);

    // conv2: pull(hbf bf16) -> aggbf; MFMA GEMM in-place -> z (= aggbf)
    k_pull<1><<<pullBlocks, 256, 0, stream>>>(hbf, cnt, adjB, dinv, aggbf, N);
    k_gemm_mfma<0><<<640, 256, 0, stream>>>(aggbf, W1, b1, aggbf, N);

    // final gather
    k_gather<<<(P * 32 + 255) / 256, 256, 0, stream>>>(seq, P, aggbf, emb, N,
                                                       (float*)d_out);
}

// Round 7
// 373.484 us; speedup vs baseline: 15.6053x; 1.2332x over previous
//
#include <hip/hip_runtime.h>

#define HDIM 128
#define OFF_SPECIAL 2
#define BSTRIDE 48   // bucket slots per node; deg~Poisson(16), P(deg>=48)~5e-11

typedef __attribute__((ext_vector_type(8))) short bf16x8;
typedef __attribute__((ext_vector_type(4))) float f32x4;

__device__ __forceinline__ float bf2f(unsigned short u) {
    union { unsigned int i; float f; } v;
    v.i = ((unsigned int)u) << 16;
    return v.f;
}
__device__ __forceinline__ unsigned short f2bf(float f) {
    union { float f; unsigned int i; } v;
    v.f = f;
    unsigned int x = v.i;
    x += 0x7FFFu + ((x >> 16) & 1u);   // RNE; data has no NaNs
    return (unsigned short)(x >> 16);
}

#define FILL_BLOCKS 1024   // 128 block-sets x 8 partitions
#define CAST_BLOCKS 512

// --- fused: (a) XCD-partitioned one-pass bucket CSR, (b) emb fp32->bf16 cast.
// Fill blocks: partition = blockIdx & 7; only edges with dst in that node-range
// are committed, so (assuming round-robin blockIdx->XCD dispatch) each node's
// bucket cache line is dirtied in a single XCD's L2 -> ~1 eviction per line.
// Cast blocks (blockIdx >= FILL_BLOCKS) grid-stride convert emb to bf16.
__global__ void k_fill_cast(const int* __restrict__ src, const int* __restrict__ dst,
                            int E, int* __restrict__ cnt, int* __restrict__ adjB,
                            int partN,
                            const float* __restrict__ emb,
                            unsigned short* __restrict__ embbf, int n4) {
    int tid = threadIdx.x;
    if (blockIdx.x < FILL_BLOCKS) {
        int part = blockIdx.x & 7;
        int blk  = blockIdx.x >> 3;
        int lo = part * partN;
        int hi = lo + partN;            // hi may exceed N; dst < N always
        int stride = (FILL_BLOCKS >> 3) * 256;
        for (int e = blk * 256 + tid; e < E; e += stride) {
            int d = dst[e];
            if (d >= lo && d < hi) {
                int slot = atomicAdd(&cnt[d], 1);
                if (slot < BSTRIDE) adjB[d * BSTRIDE + slot] = src[e];
            }
        }
    } else {
        int i0 = (blockIdx.x - FILL_BLOCKS) * 256 + tid;
        for (int i = i0; i < n4; i += CAST_BLOCKS * 256) {
            float4 v = ((const float4*)emb)[i];
            ushort4 o;
            o.x = f2bf(v.x); o.y = f2bf(v.y); o.z = f2bf(v.z); o.w = f2bf(v.w);
            ((ushort4*)embbf)[i] = o;
        }
    }
}

// --- dinv[i] = rsqrt(deg+1) from bucket counts
__global__ void k_dinv(const int* __restrict__ cnt, float* __restrict__ dinv, int N) {
    int i = blockIdx.x * blockDim.x + threadIdx.x;
    if (i < N) dinv[i] = rsqrtf((float)cnt[i] + 1.0f);
}

// --- pull-conv: agg[row] = x[row]*dinv[row]^2 + sum_nbr x[s]*dinv[s]*dinv[row]
// x bf16, agg bf16. One wave per row, lane l covers cols 2l,2l+1. 4-way MLP unroll.
__global__ __launch_bounds__(256, 8) void k_pull(
        const unsigned short* __restrict__ x, const int* __restrict__ cnt,
        const int* __restrict__ adjB, const float* __restrict__ dinv,
        unsigned short* __restrict__ agg, int N) {
    int row = blockIdx.x * 4 + (threadIdx.x >> 6);
    if (row >= N) return;
    int lane = threadIdx.x & 63;
    int d = cnt[row];
    if (d > BSTRIDE) d = BSTRIDE;
    const int* nbr = adjB + row * BSTRIDE;
    float dr = dinv[row];
    unsigned int cix = 2u * (unsigned int)lane;

    float ax, ay;
    {
        float sc = dr * dr;  // self-loop term
        unsigned int u = *(const unsigned int*)(x + (size_t)((unsigned)row * HDIM + cix));
        ax = bf2f((unsigned short)u) * sc;
        ay = bf2f((unsigned short)(u >> 16)) * sc;
    }
    int t = 0;
    for (; t + 4 <= d; t += 4) {
        int s0 = nbr[t + 0];
        int s1 = nbr[t + 1];
        int s2 = nbr[t + 2];
        int s3 = nbr[t + 3];
        float n0 = dinv[s0] * dr, n1 = dinv[s1] * dr;
        float n2 = dinv[s2] * dr, n3 = dinv[s3] * dr;
        unsigned int u0 = *(const unsigned int*)(x + (size_t)((unsigned)s0 * HDIM + cix));
        unsigned int u1 = *(const unsigned int*)(x + (size_t)((unsigned)s1 * HDIM + cix));
        unsigned int u2 = *(const unsigned int*)(x + (size_t)((unsigned)s2 * HDIM + cix));
        unsigned int u3 = *(const unsigned int*)(x + (size_t)((unsigned)s3 * HDIM + cix));
        ax = fmaf(bf2f((unsigned short)u0), n0, ax);
        ay = fmaf(bf2f((unsigned short)(u0 >> 16)), n0, ay);
        ax = fmaf(bf2f((unsigned short)u1), n1, ax);
        ay = fmaf(bf2f((unsigned short)(u1 >> 16)), n1, ay);
        ax = fmaf(bf2f((unsigned short)u2), n2, ax);
        ay = fmaf(bf2f((unsigned short)(u2 >> 16)), n2, ay);
        ax = fmaf(bf2f((unsigned short)u3), n3, ax);
        ay = fmaf(bf2f((unsigned short)(u3 >> 16)), n3, ay);
    }
    for (; t < d; ++t) {
        int s = nbr[t];
        float nr = dinv[s] * dr;
        unsigned int u = *(const unsigned int*)(x + (size_t)((unsigned)s * HDIM + cix));
        ax = fmaf(bf2f((unsigned short)u), nr, ax);
        ay = fmaf(bf2f((unsigned short)(u >> 16)), nr, ay);
    }
    unsigned int pack = (unsigned int)f2bf(ax) | ((unsigned int)f2bf(ay) << 16);
    *(unsigned int*)(agg + (size_t)((unsigned)row * HDIM + cix)) = pack;
}

// --- MFMA GEMM: out[N][128] = A[N][128](bf16) @ W[128][128](fp32->bf16) + b (+ReLU).
// Wave computes a 16-row stripe; 8 col-tiles x 4 K-steps of 16x16x32 MFMA.
// In-place (out==A) safe: each output row depends only on its own input row,
// loaded to registers before any store. Tail overreads stay inside workspace.
template <int RELU>
__global__ __launch_bounds__(256) void k_gemm_mfma(
        const unsigned short* __restrict__ A, const float* __restrict__ W,
        const float* __restrict__ bias, unsigned short* __restrict__ out, int N) {
    __shared__ __align__(16) unsigned short Wt[HDIM * 136];  // [n][k], pad->34.8 KB
    int tid = threadIdx.x;
    for (int i = tid; i < HDIM * HDIM; i += 256) {
        int k = i >> 7, n = i & 127;
        Wt[n * 136 + k] = f2bf(W[i]);   // W[k][n] row-major
    }
    int lane = tid & 63;
    int wv = tid >> 6;
    int n15 = lane & 15, q = lane >> 4;
    float bv[8];
#pragma unroll
    for (int ct = 0; ct < 8; ++ct) bv[ct] = bias[ct * 16 + n15];
    __syncthreads();

    int nChunks = (N + 63) / 64;
    for (int c = blockIdx.x; c < nChunks; c += gridDim.x) {
        int row0 = c * 64 + wv * 16;
        const unsigned short* arow = A + (size_t)(row0 + n15) * HDIM + q * 8;
        bf16x8 a0 = *(const bf16x8*)(arow);
        bf16x8 a1 = *(const bf16x8*)(arow + 32);
        bf16x8 a2 = *(const bf16x8*)(arow + 64);
        bf16x8 a3 = *(const bf16x8*)(arow + 96);
#pragma unroll
        for (int ct = 0; ct < 8; ++ct) {
            const unsigned short* wrow = &Wt[(ct * 16 + n15) * 136 + q * 8];
            f32x4 acc = {0.f, 0.f, 0.f, 0.f};
            acc = __builtin_amdgcn_mfma_f32_16x16x32_bf16(a0, *(const bf16x8*)(wrow),      acc, 0, 0, 0);
            acc = __builtin_amdgcn_mfma_f32_16x16x32_bf16(a1, *(const bf16x8*)(wrow + 32), acc, 0, 0, 0);
            acc = __builtin_amdgcn_mfma_f32_16x16x32_bf16(a2, *(const bf16x8*)(wrow + 64), acc, 0, 0, 0);
            acc = __builtin_amdgcn_mfma_f32_16x16x32_bf16(a3, *(const bf16x8*)(wrow + 96), acc, 0, 0, 0);
#pragma unroll
            for (int r = 0; r < 4; ++r) {
                int row = row0 + q * 4 + r;
                if (row < N) {
                    float v = acc[r] + bv[ct];
                    if (RELU) v = fmaxf(v, 0.0f);
                    out[(size_t)row * HDIM + ct * 16 + n15] = f2bf(v);
                }
            }
        }
    }
}

// --- final gather: out[p] = seq[p]>=0 ? z[seq[p]] (bf16) : emb[seq[p]+2+N] (fp32).
__global__ void k_gather(const int* __restrict__ seq, int P,
                         const unsigned short* __restrict__ z,
                         const float* __restrict__ emb, int N,
                         float* __restrict__ out) {
    int gid = blockIdx.x * blockDim.x + threadIdx.x;
    int p = gid >> 5, c = gid & 31;
    if (p >= P) return;
    int sv = seq[p];
    float4 v;
    if (sv >= 0) {
        uint2 u = *(const uint2*)(z + (size_t)sv * HDIM + c * 4);
        v = make_float4(bf2f((unsigned short)u.x), bf2f((unsigned short)(u.x >> 16)),
                        bf2f((unsigned short)u.y), bf2f((unsigned short)(u.y >> 16)));
    } else {
        v = *(const float4*)(emb + (size_t)(sv + OFF_SPECIAL + N) * HDIM + c * 4);
    }
    *(float4*)(out + (size_t)p * HDIM + c * 4) = v;
}

extern "C" void kernel_launch(void* const* d_in, const int* in_sizes, int n_in,
                              void* d_out, int out_size, void* d_ws, size_t ws_size,
                              hipStream_t stream) {
    const float* emb = (const float*)d_in[0];
    const float* W0  = (const float*)d_in[1];
    const float* b0  = (const float*)d_in[2];
    const float* W1  = (const float*)d_in[3];
    const float* b1  = (const float*)d_in[4];
    const int* ei  = (const int*)d_in[5];
    const int* seq = (const int*)d_in[6];

    int N = in_sizes[0] / HDIM - OFF_SPECIAL;   // 100000
    int E = in_sizes[5] / 2;                    // 1600000
    int P = in_sizes[6];                        // 32768
    const int* srcp = ei;
    const int* dstp = ei + E;

    // workspace: aggbf 25.6 | buf1 (embbf, later hbf) 25.6 | adjB 19.2 | cnt | dinv
    //            => ~71.3 MB (embbf/hbf lifetimes disjoint: embbf dies at pull1,
    //               hbf is written by gemm1 afterwards)
    char* ws = (char*)d_ws;
    size_t off = 0;
    auto alloc = [&](size_t bytes) {
        void* p = ws + off;
        off = (off + bytes + 255) & ~(size_t)255;
        return p;
    };
    unsigned short* aggbf = (unsigned short*)alloc((size_t)N * HDIM * sizeof(unsigned short));
    unsigned short* buf1  = (unsigned short*)alloc((size_t)N * HDIM * sizeof(unsigned short));
    int*   adjB = (int*)alloc((size_t)N * BSTRIDE * sizeof(int));
    int*   cnt  = (int*)alloc((size_t)N * sizeof(int));
    float* dinv = (float*)alloc((size_t)N * sizeof(float));

    hipMemsetAsync(cnt, 0, (size_t)N * sizeof(int), stream);

    int partN = (N + 7) / 8;
    int n4 = N * HDIM / 4;
    k_fill_cast<<<FILL_BLOCKS + CAST_BLOCKS, 256, 0, stream>>>(
        srcp, dstp, E, cnt, adjB, partN, emb, buf1, n4);
    k_dinv<<<(N + 255) / 256, 256, 0, stream>>>(cnt, dinv, N);

    int pullBlocks = (N + 3) / 4;

    // conv1: pull(embbf=buf1) -> aggbf; MFMA GEMM+ReLU -> hbf (=buf1, overwrites embbf)
    k_pull<<<pullBlocks, 256, 0, stream>>>(buf1, cnt, adjB, dinv, aggbf, N);
    k_gemm_mfma<1><<<640, 256, 0, stream>>>(aggbf, W0, b0, buf1, N);

    // conv2: pull(hbf=buf1) -> aggbf; MFMA GEMM in-place -> z (= aggbf)
    k_pull<<<pullBlocks, 256, 0, stream>>>(buf1, cnt, adjB, dinv, aggbf, N);
    k_gemm_mfma<0><<<640, 256, 0, stream>>>(aggbf, W1, b1, aggbf, N);

    // final gather
    k_gather<<<(P * 32 + 255) / 256, 256, 0, stream>>>(seq, P, aggbf, emb, N,
                                                       (float*)d_out);
}